// Round 3
// baseline (607.416 us; speedup 1.0000x reference)
//
#include <hip/hip_runtime.h>

#define M1 98304
#define RDIM 512
#define FDIM 2048
#define SDIM 96

typedef __attribute__((ext_vector_type(8))) __bf16 bf16x8;
typedef __attribute__((ext_vector_type(4))) float f32x4;

union U16x8 { uint4 u; unsigned short s[8]; };

__device__ __forceinline__ float bf2f(unsigned short u){
  union { unsigned int i; float f; } v; v.i = ((unsigned int)u) << 16; return v.f;
}
__device__ __forceinline__ unsigned short f2bf(float f){
  union { float f; unsigned int i; } v; v.f = f;
  unsigned int r = v.i + 0x7FFFu + ((v.i >> 16) & 1u);
  return (unsigned short)(r >> 16);
}
__device__ __forceinline__ float fast_tanh(float x){
  float e = __expf(2.f * x);
  return 1.f - 2.f / (e + 1.f);
}
__device__ __forceinline__ void gld_lds16(const void* g, void* l){
  __builtin_amdgcn_global_load_lds((const __attribute__((address_space(1))) void*)g,
                                   (__attribute__((address_space(3))) void*)l, 16, 0, 0);
}
__device__ __forceinline__ f32x4 mfma16(bf16x8 a, bf16x8 b, f32x4 c){
  return __builtin_amdgcn_mfma_f32_16x16x32_bf16(a, b, c, 0, 0, 0);
}

// ---------------- convert / split kernels ----------------
// A-side cat layout: [hi | lo | hi]   (activations)
__device__ __forceinline__ void cat_store_a(const float* __restrict__ src,
                                            unsigned short* __restrict__ dst, int idx){
  float x = src[idx];
  int r = idx >> 9, c = idx & 511;
  unsigned short hi = f2bf(x);
  unsigned short lo = f2bf(x - bf2f(hi));
  unsigned short* p = dst + (long)r * 1536 + c;
  p[0] = hi; p[512] = lo; p[1024] = hi;
}
// W-side cat layout: [whi | whi | wlo]  (weights) — so dot = hi*whi + lo*whi + hi*wlo
__device__ __forceinline__ void cat_store_w(const float* __restrict__ src,
                                            unsigned short* __restrict__ dst, int idx){
  float x = src[idx];
  int r = idx >> 9, c = idx & 511;
  unsigned short hi = f2bf(x);
  unsigned short lo = f2bf(x - bf2f(hi));
  unsigned short* p = dst + (long)r * 1536 + c;
  p[0] = hi; p[512] = hi; p[1024] = lo;
}

__global__ void k_convert(const float* W_ae, const float* W_c, const float* W_s,
                          const float* W_h, const float* W_o,
                          const float* h, const float* sent,
                          unsigned short* W_ae_bf, unsigned short* W_c_bf,
                          unsigned short* W_s_cat, unsigned short* W_h_cat,
                          unsigned short* W_o_cat, unsigned short* h_cat,
                          unsigned short* s_cat){
  int idx = blockIdx.x * 256 + threadIdx.x;
  switch (blockIdx.y) {
    case 0: if (idx < 512*2048) W_ae_bf[idx] = f2bf(W_ae[idx]); break;
    case 1: if (idx < 512*512)  W_c_bf[idx]  = f2bf(W_c[idx]);  break;
    case 2: if (idx < 512*512)  cat_store_w(W_s, W_s_cat, idx); break;
    case 3: if (idx < 512*512)  cat_store_w(W_h, W_h_cat, idx); break;
    case 4: if (idx < 512*512)  cat_store_w(W_o, W_o_cat, idx); break;
    case 5: if (idx < 1024*512) cat_store_a(h, h_cat, idx); break;
    case 6: if (idx < 1024*512) cat_store_a(sent, s_cat, idx); break;
  }
}

// ---------------- GEMM1: att = relu(att_feats @ W_ae^T + b_ae), bf16 out ----
__global__ __launch_bounds__(512) void k_gemm1(
    const float* __restrict__ Af, const unsigned short* __restrict__ Wb,
    const float* __restrict__ bias, unsigned short* __restrict__ Cout){
  __shared__ __align__(16) unsigned short As[128*32];
  __shared__ __align__(16) unsigned short Bs[512*32];
  const int tid = threadIdx.x;
  const int w = tid >> 6, l = tid & 63;
  const int wm = w >> 2, wn = w & 3;
  const long m0 = (long)blockIdx.x * 128;
  f32x4 zero = {0.f,0.f,0.f,0.f};
  f32x4 acc[4][8];
#pragma unroll
  for (int i = 0; i < 4; ++i)
#pragma unroll
    for (int j = 0; j < 8; ++j) acc[i][j] = zero;

  const int arow = tid >> 2, aslot = tid & 3;
  const float* aptr = Af + (m0 + arow) * FDIM + aslot * 8;
  // swizzled A write slot: aslot ^ ((arow>>1)&3)
  unsigned short* awr = As + arow*32 + ((aslot ^ ((arow>>1)&3)) * 8);
  const int bsl = (l & 3) ^ ((l >> 3) & 3);   // pre-swizzled global k-group for gld_lds
  const int brow_l = l >> 2;

  for (int kt = 0; kt < FDIM/32; ++kt) {
    const int k0 = kt * 32;
#pragma unroll
    for (int i = 0; i < 4; ++i) {
      int row = w*64 + i*16 + brow_l;
      gld_lds16(Wb + (long)row * FDIM + k0 + bsl*8, Bs + w*2048 + i*512);
    }
    const float4* ap = reinterpret_cast<const float4*>(aptr + k0);
    float4 v0 = ap[0], v1 = ap[1];
    U16x8 pk;
    pk.s[0]=f2bf(v0.x); pk.s[1]=f2bf(v0.y); pk.s[2]=f2bf(v0.z); pk.s[3]=f2bf(v0.w);
    pk.s[4]=f2bf(v1.x); pk.s[5]=f2bf(v1.y); pk.s[6]=f2bf(v1.z); pk.s[7]=f2bf(v1.w);
    *reinterpret_cast<uint4*>(awr) = pk.u;
    __syncthreads();
    bf16x8 afr[4], bfr[8];
    const int g = l >> 4, r15 = l & 15;
    const int rs = (r15 >> 1) & 3;            // read-side swizzle
#pragma unroll
    for (int i = 0; i < 4; ++i)
      afr[i] = *reinterpret_cast<const bf16x8*>(As + (wm*64 + i*16 + r15)*32 + ((g ^ rs)*8));
#pragma unroll
    for (int j = 0; j < 8; ++j)
      bfr[j] = *reinterpret_cast<const bf16x8*>(Bs + (wn*128 + j*16 + r15)*32 + ((g ^ rs)*8));
#pragma unroll
    for (int i = 0; i < 4; ++i)
#pragma unroll
      for (int j = 0; j < 8; ++j)
        acc[i][j] = mfma16(afr[i], bfr[j], acc[i][j]);
    __syncthreads();
  }
  const int r15 = l & 15, g = l >> 4;
#pragma unroll
  for (int i = 0; i < 4; ++i)
#pragma unroll
    for (int r = 0; r < 4; ++r) {
      long m = m0 + wm*64 + i*16 + g*4 + r;
#pragma unroll
      for (int j = 0; j < 8; ++j) {
        int n = wn*128 + j*16 + r15;
        float x = acc[i][j][r] + bias[n];
        Cout[m * RDIM + n] = f2bf(x > 0.f ? x : 0.f);
      }
    }
}

// ---- GEMM2: logits[m] = sum_n tanh(att@W_c^T + b_c + h_e[b]) * W_al[n] ----
__global__ __launch_bounds__(512) void k_gemm2(
    const unsigned short* __restrict__ Abf, const unsigned short* __restrict__ Wb,
    const float* __restrict__ bias, const float* __restrict__ h_e,
    const float* __restrict__ W_al, float* __restrict__ logits){
  __shared__ __align__(16) unsigned short As[128*32];
  __shared__ __align__(16) unsigned short Bs[512*32];
  __shared__ float part[128][4];
  const int tid = threadIdx.x;
  const int w = tid >> 6, l = tid & 63;
  const int wm = w >> 2, wn = w & 3;
  const long m0 = (long)blockIdx.x * 128;
  f32x4 zero = {0.f,0.f,0.f,0.f};
  f32x4 acc[4][8];
#pragma unroll
  for (int i = 0; i < 4; ++i)
#pragma unroll
    for (int j = 0; j < 8; ++j) acc[i][j] = zero;

  const int crow = l >> 2;
  const int bsl = (l & 3) ^ ((l >> 3) & 3);

  for (int kt = 0; kt < RDIM/32; ++kt) {
    const int k0 = kt * 32;
    gld_lds16(Abf + (m0 + w*16 + crow) * RDIM + k0 + bsl*8, As + w*512);
#pragma unroll
    for (int i = 0; i < 4; ++i) {
      int row = w*64 + i*16 + crow;
      gld_lds16(Wb + (long)row * RDIM + k0 + bsl*8, Bs + w*2048 + i*512);
    }
    __syncthreads();
    bf16x8 afr[4], bfr[8];
    const int g = l >> 4, r15 = l & 15;
    const int rs = (r15 >> 1) & 3;
#pragma unroll
    for (int i = 0; i < 4; ++i)
      afr[i] = *reinterpret_cast<const bf16x8*>(As + (wm*64 + i*16 + r15)*32 + ((g ^ rs)*8));
#pragma unroll
    for (int j = 0; j < 8; ++j)
      bfr[j] = *reinterpret_cast<const bf16x8*>(Bs + (wn*128 + j*16 + r15)*32 + ((g ^ rs)*8));
#pragma unroll
    for (int i = 0; i < 4; ++i)
#pragma unroll
      for (int j = 0; j < 8; ++j)
        acc[i][j] = mfma16(afr[i], bfr[j], acc[i][j]);
    __syncthreads();
  }
  const int r15 = l & 15, g = l >> 4;
#pragma unroll
  for (int i = 0; i < 4; ++i)
#pragma unroll
    for (int r = 0; r < 4; ++r) {
      int lrow = wm*64 + i*16 + g*4 + r;
      long m = m0 + lrow;
      int b = (int)(m / SDIM);
      const float* hrow = h_e + (long)b * RDIM;
      float s = 0.f;
#pragma unroll
      for (int j = 0; j < 8; ++j) {
        int n = wn*128 + j*16 + r15;
        float x = acc[i][j][r] + bias[n] + hrow[n];
        s += fast_tanh(x) * W_al[n];
      }
      s += __shfl_xor(s, 1); s += __shfl_xor(s, 2);
      s += __shfl_xor(s, 4); s += __shfl_xor(s, 8);
      if (r15 == 0) part[lrow][wn] = s;
    }
  __syncthreads();
  if (tid < 128)
    logits[m0 + tid] = part[tid][0] + part[tid][1] + part[tid][2] + part[tid][3];
}

// ---------------- small GEMM (K=1536 hi/lo-cat), f32 out --------------------
__global__ __launch_bounds__(256) void k_gemm_small(
    const unsigned short* __restrict__ Abf, const unsigned short* __restrict__ Wb,
    const float* __restrict__ bias, float* __restrict__ Cout, int do_tanh){
  __shared__ __align__(16) unsigned short As[64*32];
  __shared__ __align__(16) unsigned short Bs[64*32];
  const int tid = threadIdx.x;
  const int w = tid >> 6, l = tid & 63;
  const int wm = w >> 1, wn = w & 1;
  const int m0 = (blockIdx.x >> 3) * 64, n0 = (blockIdx.x & 7) * 64;
  const int K = 1536;
  f32x4 zero = {0.f,0.f,0.f,0.f};
  f32x4 acc[2][2];
#pragma unroll
  for (int i = 0; i < 2; ++i)
#pragma unroll
    for (int j = 0; j < 2; ++j) acc[i][j] = zero;

  const int crow = l >> 2;
  const int bsl = (l & 3) ^ ((l >> 3) & 3);

  for (int kt = 0; kt < 48; ++kt) {
    const int k0 = kt * 32;
    gld_lds16(Abf + (long)(m0 + w*16 + crow)*K + k0 + bsl*8, As + w*512);
    gld_lds16(Wb  + (long)(n0 + w*16 + crow)*K + k0 + bsl*8, Bs + w*512);
    __syncthreads();
    bf16x8 afr[2], bfr[2];
    const int g = l >> 4, r15 = l & 15;
    const int rs = (r15 >> 1) & 3;
#pragma unroll
    for (int i = 0; i < 2; ++i)
      afr[i] = *reinterpret_cast<const bf16x8*>(As + (wm*32 + i*16 + r15)*32 + ((g ^ rs)*8));
#pragma unroll
    for (int j = 0; j < 2; ++j)
      bfr[j] = *reinterpret_cast<const bf16x8*>(Bs + (wn*32 + j*16 + r15)*32 + ((g ^ rs)*8));
#pragma unroll
    for (int i = 0; i < 2; ++i)
#pragma unroll
      for (int j = 0; j < 2; ++j)
        acc[i][j] = mfma16(afr[i], bfr[j], acc[i][j]);
    __syncthreads();
  }
  const int r15 = l & 15, g = l >> 4;
#pragma unroll
  for (int i = 0; i < 2; ++i)
#pragma unroll
    for (int r = 0; r < 4; ++r) {
      int m = m0 + wm*32 + i*16 + g*4 + r;
#pragma unroll
      for (int j = 0; j < 2; ++j) {
        int n = n0 + wn*32 + j*16 + r15;
        float x = acc[i][j][r] + bias[n];
        if (do_tanh) x = fast_tanh(x);
        Cout[(long)m * 512 + n] = x;
      }
    }
}

// ---------------- sentinel logit ----------------
__global__ __launch_bounds__(256) void k_logit_sent(
    const float* __restrict__ sent_e, const float* __restrict__ h_e,
    const float* __restrict__ W_al, float* __restrict__ lsent){
  const int w = threadIdx.x >> 6, l = threadIdx.x & 63;
  const int b = blockIdx.x * 4 + w;
  float s = 0.f;
  for (int a = l; a < 512; a += 64)
    s += fast_tanh(sent_e[(long)b*512 + a] + h_e[(long)b*512 + a]) * W_al[a];
  s += __shfl_xor(s, 1); s += __shfl_xor(s, 2); s += __shfl_xor(s, 4);
  s += __shfl_xor(s, 8); s += __shfl_xor(s, 16); s += __shfl_xor(s, 32);
  if (l == 0) lsent[b] = s;
}

// ---------------- softmax + cHat + atten_out(hi/lo cat) ----------------
__global__ __launch_bounds__(512) void k_softmax_chat(
    const float* __restrict__ lsent, const float* __restrict__ logits,
    const unsigned short* __restrict__ att_bf, const float* __restrict__ sent,
    const float* __restrict__ h, unsigned short* __restrict__ atten_cat){
  __shared__ float lg[97];
  __shared__ float alpha[97];
  __shared__ float ssum_s;
  const int b = blockIdx.x;
  const int tid = threadIdx.x;
  if (tid == 0) lg[0] = lsent[b];
  else if (tid <= 96) lg[tid] = logits[(long)b*96 + tid - 1];
  __syncthreads();
  if (tid < 64) {
    float m = -1e30f;
    for (int i = tid; i < 97; i += 64) m = fmaxf(m, lg[i]);
#pragma unroll
    for (int k = 1; k < 64; k <<= 1) m = fmaxf(m, __shfl_xor(m, k));
    float ss = 0.f;
    for (int i = tid; i < 97; i += 64) { float e = __expf(lg[i] - m); alpha[i] = e; ss += e; }
#pragma unroll
    for (int k = 1; k < 64; k <<= 1) ss += __shfl_xor(ss, k);
    if (tid == 0) ssum_s = ss;
  }
  __syncthreads();
  if (tid < 97) alpha[tid] *= (1.f / ssum_s);
  __syncthreads();
  const int t = tid;
  float accv = alpha[0] * sent[(long)b*512 + t];
  const unsigned short* arow = att_bf + (long)b * SDIM * RDIM + t;
#pragma unroll 4
  for (int s = 0; s < SDIM; ++s)
    accv += alpha[s+1] * bf2f(arow[(long)s * RDIM]);
  float x = accv + h[(long)b*512 + t];
  unsigned short hi = f2bf(x);
  unsigned short lo = f2bf(x - bf2f(hi));
  unsigned short* p = atten_cat + (long)b*1536 + t;
  p[0] = hi; p[512] = lo; p[1024] = hi;   // A-side layout
}

extern "C" void kernel_launch(void* const* d_in, const int* in_sizes, int n_in,
                              void* d_out, int out_size, void* d_ws, size_t ws_size,
                              hipStream_t stream){
  (void)in_sizes; (void)n_in; (void)out_size; (void)ws_size;
  const float* h    = (const float*)d_in[0];
  const float* sent = (const float*)d_in[1];
  const float* feats= (const float*)d_in[2];
  const float* W_ae = (const float*)d_in[3];
  const float* b_ae = (const float*)d_in[4];
  const float* W_c  = (const float*)d_in[5];
  const float* b_c  = (const float*)d_in[6];
  const float* W_s  = (const float*)d_in[7];
  const float* b_s  = (const float*)d_in[8];
  const float* W_h  = (const float*)d_in[9];
  const float* b_h  = (const float*)d_in[10];
  const float* W_al = (const float*)d_in[11];
  const float* W_o  = (const float*)d_in[13];
  const float* b_o  = (const float*)d_in[14];
  float* out = (float*)d_out;

  char* p = (char*)d_ws;
  unsigned short* att_bf  = (unsigned short*)p; p += (size_t)M1*512*2;
  unsigned short* W_ae_bf = (unsigned short*)p; p += (size_t)512*2048*2;
  unsigned short* W_c_bf  = (unsigned short*)p; p += (size_t)512*512*2;
  unsigned short* W_s_cat = (unsigned short*)p; p += (size_t)512*1536*2;
  unsigned short* W_h_cat = (unsigned short*)p; p += (size_t)512*1536*2;
  unsigned short* W_o_cat = (unsigned short*)p; p += (size_t)512*1536*2;
  unsigned short* h_cat   = (unsigned short*)p; p += (size_t)1024*1536*2;
  unsigned short* s_cat   = (unsigned short*)p; p += (size_t)1024*1536*2;
  unsigned short* at_cat  = (unsigned short*)p; p += (size_t)1024*1536*2;
  float* h_e    = (float*)p; p += (size_t)1024*512*4;
  float* sent_e = (float*)p; p += (size_t)1024*512*4;
  float* logits = (float*)p; p += (size_t)M1*4;
  float* lsent  = (float*)p; p += (size_t)1024*4;

  k_convert<<<dim3(4096,7), 256, 0, stream>>>(W_ae, W_c, W_s, W_h, W_o, h, sent,
        W_ae_bf, W_c_bf, W_s_cat, W_h_cat, W_o_cat, h_cat, s_cat);
  k_gemm_small<<<128, 256, 0, stream>>>(h_cat, W_h_cat, b_h, h_e, 0);
  k_gemm_small<<<128, 256, 0, stream>>>(s_cat, W_s_cat, b_s, sent_e, 0);
  k_gemm1<<<768, 512, 0, stream>>>(feats, W_ae_bf, b_ae, att_bf);
  k_logit_sent<<<256, 256, 0, stream>>>(sent_e, h_e, W_al, lsent);
  k_gemm2<<<768, 512, 0, stream>>>(att_bf, W_c_bf, b_c, h_e, W_al, logits);
  k_softmax_chat<<<1024, 512, 0, stream>>>(lsent, logits, att_bf, sent, h, at_cat);
  k_gemm_small<<<128, 256, 0, stream>>>(at_cat, W_o_cat, b_o, out, 1);
}

// Round 4
// 546.351 us; speedup vs baseline: 1.1118x; 1.1118x over previous
//
#include <hip/hip_runtime.h>

#define M1 98304
#define RDIM 512
#define FDIM 2048
#define SDIM 96

typedef __attribute__((ext_vector_type(8))) __bf16 bf16x8;
typedef __attribute__((ext_vector_type(4))) float f32x4;

__device__ __forceinline__ float bf2f(unsigned short u){
  union { unsigned int i; float f; } v; v.i = ((unsigned int)u) << 16; return v.f;
}
__device__ __forceinline__ unsigned short f2bf(float f){
  union { float f; unsigned int i; } v; v.f = f;
  unsigned int r = v.i + 0x7FFFu + ((v.i >> 16) & 1u);
  return (unsigned short)(r >> 16);
}
__device__ __forceinline__ float fast_tanh(float x){
  float e = __expf(2.f * x);
  return 1.f - 2.f / (e + 1.f);
}
__device__ __forceinline__ void gld_lds16(const void* g, void* l){
  __builtin_amdgcn_global_load_lds((const __attribute__((address_space(1))) void*)g,
                                   (__attribute__((address_space(3))) void*)l, 16, 0, 0);
}
__device__ __forceinline__ f32x4 mfma16(bf16x8 a, bf16x8 b, f32x4 c){
  return __builtin_amdgcn_mfma_f32_16x16x32_bf16(a, b, c, 0, 0, 0);
}

// ---------------- convert / split kernels ----------------
// A-side cat layout: [hi | lo | hi]   (activations)
__device__ __forceinline__ void cat_store_a(const float* __restrict__ src,
                                            unsigned short* __restrict__ dst, int idx){
  float x = src[idx];
  int r = idx >> 9, c = idx & 511;
  unsigned short hi = f2bf(x);
  unsigned short lo = f2bf(x - bf2f(hi));
  unsigned short* p = dst + (long)r * 1536 + c;
  p[0] = hi; p[512] = lo; p[1024] = hi;
}
// W-side cat layout: [whi | whi | wlo]  — dot = hi*whi + lo*whi + hi*wlo
__device__ __forceinline__ void cat_store_w(const float* __restrict__ src,
                                            unsigned short* __restrict__ dst, int idx){
  float x = src[idx];
  int r = idx >> 9, c = idx & 511;
  unsigned short hi = f2bf(x);
  unsigned short lo = f2bf(x - bf2f(hi));
  unsigned short* p = dst + (long)r * 1536 + c;
  p[0] = hi; p[512] = hi; p[1024] = lo;
}

__global__ void k_convert(const float* W_ae, const float* W_c, const float* W_s,
                          const float* W_h, const float* W_o,
                          const float* h, const float* sent,
                          unsigned short* W_ae_bf, unsigned short* W_c_bf,
                          unsigned short* W_s_cat, unsigned short* W_h_cat,
                          unsigned short* W_o_cat, unsigned short* h_cat,
                          unsigned short* s_cat){
  int idx = blockIdx.x * 256 + threadIdx.x;
  switch (blockIdx.y) {
    case 0: if (idx < 512*2048) W_ae_bf[idx] = f2bf(W_ae[idx]); break;
    case 1: if (idx < 512*512)  W_c_bf[idx]  = f2bf(W_c[idx]);  break;
    case 2: if (idx < 512*512)  cat_store_w(W_s, W_s_cat, idx); break;
    case 3: if (idx < 512*512)  cat_store_w(W_h, W_h_cat, idx); break;
    case 4: if (idx < 512*512)  cat_store_w(W_o, W_o_cat, idx); break;
    case 5: if (idx < 1024*512) cat_store_a(h, h_cat, idx); break;
    case 6: if (idx < 1024*512) cat_store_a(sent, s_cat, idx); break;
  }
}

// ---------------- GEMM1: att = relu(att_feats @ W_ae^T + b_ae) --------------
// 64x512 tile, BK=32, 2-phase double-buffered pipeline, 8 waves (2M x 4N).
__global__ __launch_bounds__(512, 4) void k_gemm1(
    const float* __restrict__ Af, const unsigned short* __restrict__ Wb,
    const float* __restrict__ bias, unsigned short* __restrict__ Cout){
  __shared__ __align__(16) unsigned short As[2][64*32];
  __shared__ __align__(16) unsigned short Bs[2][512*32];
  const int tid = threadIdx.x;
  const int w = tid >> 6, l = tid & 63;
  const int wm = w >> 2, wn = w & 3;
  const long m0 = (long)blockIdx.x * 64;
  f32x4 acc[2][8];
#pragma unroll
  for (int i = 0; i < 2; ++i)
#pragma unroll
    for (int j = 0; j < 8; ++j) acc[i][j] = f32x4{0.f,0.f,0.f,0.f};

  // A staging: 64 rows x 8 quarter-slots of 4 floats
  const int arow = tid >> 3, aq = tid & 7;
  const float* aptr = Af + (m0 + arow) * FDIM + aq * 4;
  const int aswz = (((aq >> 1) ^ ((arow >> 1) & 3)) * 8) + (aq & 1) * 4; // swizzled short offset
  // B staging: pre-swizzled global source for gld_lds (verified R3 pattern)
  const int bsl = (l & 3) ^ ((l >> 3) & 3);
  const unsigned short* bptr = Wb + (long)(w*64 + (l >> 2)) * FDIM + bsl * 8;
  const int g = l >> 4, r15 = l & 15;
  const int rs = (r15 >> 1) & 3;            // read-side swizzle (matches write)

  // prologue: stage tile 0 into buf 0
  {
#pragma unroll
    for (int i = 0; i < 4; ++i)
      gld_lds16(bptr + (long)i*16*FDIM, &Bs[0][w*2048 + i*512]);
    float4 v = *reinterpret_cast<const float4*>(aptr);
    ushort4 pk; pk.x=f2bf(v.x); pk.y=f2bf(v.y); pk.z=f2bf(v.z); pk.w=f2bf(v.w);
    *reinterpret_cast<ushort4*>(&As[0][arow*32 + aswz]) = pk;
  }
  __syncthreads();
  int cur = 0;
  for (int kt = 1; kt < FDIM/32; ++kt) {
    const int k0 = kt * 32;
    // prefetch tile kt into buf cur^1 (flies under compute below)
    float4 v = *reinterpret_cast<const float4*>(aptr + k0);
#pragma unroll
    for (int i = 0; i < 4; ++i)
      gld_lds16(bptr + (long)i*16*FDIM + k0, &Bs[cur^1][w*2048 + i*512]);
    // compute tile kt-1 from buf cur
    bf16x8 af0 = *reinterpret_cast<const bf16x8*>(&As[cur][(wm*32 + r15)*32 + ((g^rs)*8)]);
    bf16x8 af1 = *reinterpret_cast<const bf16x8*>(&As[cur][(wm*32 + 16 + r15)*32 + ((g^rs)*8)]);
#pragma unroll
    for (int j = 0; j < 8; ++j) {
      bf16x8 bfj = *reinterpret_cast<const bf16x8*>(&Bs[cur][(wn*128 + j*16 + r15)*32 + ((g^rs)*8)]);
      acc[0][j] = mfma16(af0, bfj, acc[0][j]);
      acc[1][j] = mfma16(af1, bfj, acc[1][j]);
    }
    // convert+write prefetched A into buf cur^1
    ushort4 pk; pk.x=f2bf(v.x); pk.y=f2bf(v.y); pk.z=f2bf(v.z); pk.w=f2bf(v.w);
    *reinterpret_cast<ushort4*>(&As[cur^1][arow*32 + aswz]) = pk;
    __syncthreads();
    cur ^= 1;
  }
  // final tile
  {
    bf16x8 af0 = *reinterpret_cast<const bf16x8*>(&As[cur][(wm*32 + r15)*32 + ((g^rs)*8)]);
    bf16x8 af1 = *reinterpret_cast<const bf16x8*>(&As[cur][(wm*32 + 16 + r15)*32 + ((g^rs)*8)]);
#pragma unroll
    for (int j = 0; j < 8; ++j) {
      bf16x8 bfj = *reinterpret_cast<const bf16x8*>(&Bs[cur][(wn*128 + j*16 + r15)*32 + ((g^rs)*8)]);
      acc[0][j] = mfma16(af0, bfj, acc[0][j]);
      acc[1][j] = mfma16(af1, bfj, acc[1][j]);
    }
  }
  // epilogue
  float bb[8];
#pragma unroll
  for (int j = 0; j < 8; ++j) bb[j] = bias[wn*128 + j*16 + r15];
#pragma unroll
  for (int i = 0; i < 2; ++i)
#pragma unroll
    for (int r = 0; r < 4; ++r) {
      long m = m0 + wm*32 + i*16 + g*4 + r;
#pragma unroll
      for (int j = 0; j < 8; ++j) {
        int n = wn*128 + j*16 + r15;
        float x = acc[i][j][r] + bb[j];
        Cout[m * RDIM + n] = f2bf(x > 0.f ? x : 0.f);
      }
    }
}

// ---- GEMM2: logits[m] = sum_n tanh(att@W_c^T + b_c + h_e[b]) * W_al[n] ----
// 64x512 tile, BK=32, same 2-phase pipeline.
__global__ __launch_bounds__(512, 4) void k_gemm2(
    const unsigned short* __restrict__ Abf, const unsigned short* __restrict__ Wb,
    const float* __restrict__ bias, const float* __restrict__ h_e,
    const float* __restrict__ W_al, float* __restrict__ logits){
  __shared__ __align__(16) unsigned short As[2][64*32];
  __shared__ __align__(16) unsigned short Bs[2][512*32];
  __shared__ float part[64][4];
  const int tid = threadIdx.x;
  const int w = tid >> 6, l = tid & 63;
  const int wm = w >> 2, wn = w & 3;
  const long m0 = (long)blockIdx.x * 64;
  f32x4 acc[2][8];
#pragma unroll
  for (int i = 0; i < 2; ++i)
#pragma unroll
    for (int j = 0; j < 8; ++j) acc[i][j] = f32x4{0.f,0.f,0.f,0.f};

  const int bsl = (l & 3) ^ ((l >> 3) & 3);
  const unsigned short* bptr = Wb + (long)(w*64 + (l >> 2)) * RDIM + bsl * 8;
  const unsigned short* aptrg = Abf + (m0 + (w & 3)*16 + (l >> 2)) * RDIM + bsl * 8; // waves 0-3
  const int g = l >> 4, r15 = l & 15;
  const int rs = (r15 >> 1) & 3;

  {
#pragma unroll
    for (int i = 0; i < 4; ++i)
      gld_lds16(bptr + (long)i*16*RDIM, &Bs[0][w*2048 + i*512]);
    if (w < 4) gld_lds16(aptrg, &As[0][w*512]);
  }
  __syncthreads();
  int cur = 0;
  for (int kt = 1; kt < RDIM/32; ++kt) {
    const int k0 = kt * 32;
#pragma unroll
    for (int i = 0; i < 4; ++i)
      gld_lds16(bptr + (long)i*16*RDIM + k0, &Bs[cur^1][w*2048 + i*512]);
    if (w < 4) gld_lds16(aptrg + k0, &As[cur^1][w*512]);
    bf16x8 af0 = *reinterpret_cast<const bf16x8*>(&As[cur][(wm*32 + r15)*32 + ((g^rs)*8)]);
    bf16x8 af1 = *reinterpret_cast<const bf16x8*>(&As[cur][(wm*32 + 16 + r15)*32 + ((g^rs)*8)]);
#pragma unroll
    for (int j = 0; j < 8; ++j) {
      bf16x8 bfj = *reinterpret_cast<const bf16x8*>(&Bs[cur][(wn*128 + j*16 + r15)*32 + ((g^rs)*8)]);
      acc[0][j] = mfma16(af0, bfj, acc[0][j]);
      acc[1][j] = mfma16(af1, bfj, acc[1][j]);
    }
    __syncthreads();
    cur ^= 1;
  }
  {
    bf16x8 af0 = *reinterpret_cast<const bf16x8*>(&As[cur][(wm*32 + r15)*32 + ((g^rs)*8)]);
    bf16x8 af1 = *reinterpret_cast<const bf16x8*>(&As[cur][(wm*32 + 16 + r15)*32 + ((g^rs)*8)]);
#pragma unroll
    for (int j = 0; j < 8; ++j) {
      bf16x8 bfj = *reinterpret_cast<const bf16x8*>(&Bs[cur][(wn*128 + j*16 + r15)*32 + ((g^rs)*8)]);
      acc[0][j] = mfma16(af0, bfj, acc[0][j]);
      acc[1][j] = mfma16(af1, bfj, acc[1][j]);
    }
  }
  float bb[8], wa[8];
#pragma unroll
  for (int j = 0; j < 8; ++j) {
    int n = wn*128 + j*16 + r15;
    bb[j] = bias[n]; wa[j] = W_al[n];
  }
#pragma unroll
  for (int i = 0; i < 2; ++i)
#pragma unroll
    for (int r = 0; r < 4; ++r) {
      int lrow = wm*32 + i*16 + g*4 + r;
      long m = m0 + lrow;
      int b = (int)(m / SDIM);
      const float* hrow = h_e + (long)b * RDIM;
      float s = 0.f;
#pragma unroll
      for (int j = 0; j < 8; ++j) {
        int n = wn*128 + j*16 + r15;
        float x = acc[i][j][r] + bb[j] + hrow[n];
        s += fast_tanh(x) * wa[j];
      }
      s += __shfl_xor(s, 1); s += __shfl_xor(s, 2);
      s += __shfl_xor(s, 4); s += __shfl_xor(s, 8);
      if (r15 == 0) part[lrow][wn] = s;
    }
  __syncthreads();
  if (tid < 64)
    logits[m0 + tid] = part[tid][0] + part[tid][1] + part[tid][2] + part[tid][3];
}

// ---------------- small GEMM body (K=1536 hi/lo-cat), f32 out ---------------
__device__ __forceinline__ void small_gemm_body(
    const unsigned short* __restrict__ Abf, const unsigned short* __restrict__ Wb,
    const float* __restrict__ bias, float* __restrict__ Cout, int do_tanh, int bx,
    unsigned short* As, unsigned short* Bs){
  const int tid = threadIdx.x;
  const int w = tid >> 6, l = tid & 63;
  const int wm = w >> 1, wn = w & 1;
  const int m0 = (bx >> 3) * 64, n0 = (bx & 7) * 64;
  const int K = 1536;
  f32x4 acc[2][2];
#pragma unroll
  for (int i = 0; i < 2; ++i)
#pragma unroll
    for (int j = 0; j < 2; ++j) acc[i][j] = f32x4{0.f,0.f,0.f,0.f};

  const int crow = l >> 2;
  const int bsl = (l & 3) ^ ((l >> 3) & 3);

  for (int kt = 0; kt < 48; ++kt) {
    const int k0 = kt * 32;
    gld_lds16(Abf + (long)(m0 + w*16 + crow)*K + k0 + bsl*8, As + w*512);
    gld_lds16(Wb  + (long)(n0 + w*16 + crow)*K + k0 + bsl*8, Bs + w*512);
    __syncthreads();
    bf16x8 afr[2], bfr[2];
    const int g = l >> 4, r15 = l & 15;
    const int rs = (r15 >> 1) & 3;
#pragma unroll
    for (int i = 0; i < 2; ++i)
      afr[i] = *reinterpret_cast<const bf16x8*>(As + (wm*32 + i*16 + r15)*32 + ((g ^ rs)*8));
#pragma unroll
    for (int j = 0; j < 2; ++j)
      bfr[j] = *reinterpret_cast<const bf16x8*>(Bs + (wn*32 + j*16 + r15)*32 + ((g ^ rs)*8));
#pragma unroll
    for (int i = 0; i < 2; ++i)
#pragma unroll
      for (int j = 0; j < 2; ++j)
        acc[i][j] = mfma16(afr[i], bfr[j], acc[i][j]);
    __syncthreads();
  }
  const int r15 = l & 15, g = l >> 4;
#pragma unroll
  for (int i = 0; i < 2; ++i)
#pragma unroll
    for (int r = 0; r < 4; ++r) {
      int m = m0 + wm*32 + i*16 + g*4 + r;
#pragma unroll
      for (int j = 0; j < 2; ++j) {
        int n = n0 + wn*32 + j*16 + r15;
        float x = acc[i][j][r] + bias[n];
        if (do_tanh) x = fast_tanh(x);
        Cout[(long)m * 512 + n] = x;
      }
    }
}

__global__ __launch_bounds__(256) void k_gemm_small(
    const unsigned short* __restrict__ Abf, const unsigned short* __restrict__ Wb,
    const float* __restrict__ bias, float* __restrict__ Cout, int do_tanh){
  __shared__ __align__(16) unsigned short As[64*32];
  __shared__ __align__(16) unsigned short Bs[64*32];
  small_gemm_body(Abf, Wb, bias, Cout, do_tanh, blockIdx.x, As, Bs);
}

__global__ __launch_bounds__(256) void k_embed2(
    const unsigned short* __restrict__ h_cat, const unsigned short* __restrict__ W_h_cat,
    const float* __restrict__ b_h, float* __restrict__ h_e,
    const unsigned short* __restrict__ s_cat, const unsigned short* __restrict__ W_s_cat,
    const float* __restrict__ b_s, float* __restrict__ sent_e){
  __shared__ __align__(16) unsigned short As[64*32];
  __shared__ __align__(16) unsigned short Bs[64*32];
  if (blockIdx.y == 0) small_gemm_body(h_cat, W_h_cat, b_h, h_e, 0, blockIdx.x, As, Bs);
  else                 small_gemm_body(s_cat, W_s_cat, b_s, sent_e, 0, blockIdx.x, As, Bs);
}

// ------- softmax + cHat + atten_out(hi/lo cat), sentinel logit inline -------
__global__ __launch_bounds__(512) void k_softmax_chat(
    const float* __restrict__ logits, const unsigned short* __restrict__ att_bf,
    const float* __restrict__ sent, const float* __restrict__ h,
    const float* __restrict__ sent_e, const float* __restrict__ h_e,
    const float* __restrict__ W_al, unsigned short* __restrict__ atten_cat){
  __shared__ float lg[97];
  __shared__ float alpha[97];
  __shared__ float ssum_s;
  const int b = blockIdx.x;
  const int tid = threadIdx.x;
  if (tid >= 1 && tid <= 96) lg[tid] = logits[(long)b*96 + tid - 1];
  if (tid < 64) {   // sentinel logit, wave 0
    float s = 0.f;
    for (int a = tid; a < 512; a += 64)
      s += fast_tanh(sent_e[(long)b*512 + a] + h_e[(long)b*512 + a]) * W_al[a];
    s += __shfl_xor(s, 1); s += __shfl_xor(s, 2); s += __shfl_xor(s, 4);
    s += __shfl_xor(s, 8); s += __shfl_xor(s, 16); s += __shfl_xor(s, 32);
    if (tid == 0) lg[0] = s;
  }
  __syncthreads();
  if (tid < 64) {
    float m = -1e30f;
    for (int i = tid; i < 97; i += 64) m = fmaxf(m, lg[i]);
#pragma unroll
    for (int k = 1; k < 64; k <<= 1) m = fmaxf(m, __shfl_xor(m, k));
    float ss = 0.f;
    for (int i = tid; i < 97; i += 64) { float e = __expf(lg[i] - m); alpha[i] = e; ss += e; }
#pragma unroll
    for (int k = 1; k < 64; k <<= 1) ss += __shfl_xor(ss, k);
    if (tid == 0) ssum_s = ss;
  }
  __syncthreads();
  if (tid < 97) alpha[tid] *= (1.f / ssum_s);
  __syncthreads();
  const int t = tid;
  float accv = alpha[0] * sent[(long)b*512 + t];
  const unsigned short* arow = att_bf + (long)b * SDIM * RDIM + t;
#pragma unroll 4
  for (int s = 0; s < SDIM; ++s)
    accv += alpha[s+1] * bf2f(arow[(long)s * RDIM]);
  float x = accv + h[(long)b*512 + t];
  unsigned short hi = f2bf(x);
  unsigned short lo = f2bf(x - bf2f(hi));
  unsigned short* p = atten_cat + (long)b*1536 + t;
  p[0] = hi; p[512] = lo; p[1024] = hi;   // A-side layout
}

extern "C" void kernel_launch(void* const* d_in, const int* in_sizes, int n_in,
                              void* d_out, int out_size, void* d_ws, size_t ws_size,
                              hipStream_t stream){
  (void)in_sizes; (void)n_in; (void)out_size; (void)ws_size;
  const float* h    = (const float*)d_in[0];
  const float* sent = (const float*)d_in[1];
  const float* feats= (const float*)d_in[2];
  const float* W_ae = (const float*)d_in[3];
  const float* b_ae = (const float*)d_in[4];
  const float* W_c  = (const float*)d_in[5];
  const float* b_c  = (const float*)d_in[6];
  const float* W_s  = (const float*)d_in[7];
  const float* b_s  = (const float*)d_in[8];
  const float* W_h  = (const float*)d_in[9];
  const float* b_h  = (const float*)d_in[10];
  const float* W_al = (const float*)d_in[11];
  const float* W_o  = (const float*)d_in[13];
  const float* b_o  = (const float*)d_in[14];
  float* out = (float*)d_out;

  char* p = (char*)d_ws;
  unsigned short* att_bf  = (unsigned short*)p; p += (size_t)M1*512*2;
  unsigned short* W_ae_bf = (unsigned short*)p; p += (size_t)512*2048*2;
  unsigned short* W_c_bf  = (unsigned short*)p; p += (size_t)512*512*2;
  unsigned short* W_s_cat = (unsigned short*)p; p += (size_t)512*1536*2;
  unsigned short* W_h_cat = (unsigned short*)p; p += (size_t)512*1536*2;
  unsigned short* W_o_cat = (unsigned short*)p; p += (size_t)512*1536*2;
  unsigned short* h_cat   = (unsigned short*)p; p += (size_t)1024*1536*2;
  unsigned short* s_cat   = (unsigned short*)p; p += (size_t)1024*1536*2;
  unsigned short* at_cat  = (unsigned short*)p; p += (size_t)1024*1536*2;
  float* h_e    = (float*)p; p += (size_t)1024*512*4;
  float* sent_e = (float*)p; p += (size_t)1024*512*4;
  float* logits = (float*)p; p += (size_t)M1*4;

  k_convert<<<dim3(4096,7), 256, 0, stream>>>(W_ae, W_c, W_s, W_h, W_o, h, sent,
        W_ae_bf, W_c_bf, W_s_cat, W_h_cat, W_o_cat, h_cat, s_cat);
  k_embed2<<<dim3(128,2), 256, 0, stream>>>(h_cat, W_h_cat, b_h, h_e,
                                            s_cat, W_s_cat, b_s, sent_e);
  k_gemm1<<<1536, 512, 0, stream>>>(feats, W_ae_bf, b_ae, att_bf);
  k_gemm2<<<1536, 512, 0, stream>>>(att_bf, W_c_bf, b_c, h_e, W_al, logits);
  k_softmax_chat<<<1024, 512, 0, stream>>>(logits, att_bf, sent, h,
                                           sent_e, h_e, W_al, at_cat);
  k_gemm_small<<<128, 256, 0, stream>>>(at_cat, W_o_cat, b_o, out, 1);
}